// Round 3
// baseline (192.573 us; speedup 1.0000x reference)
//
#include <hip/hip_runtime.h>

// Problem constants (match reference)
constexpr int B    = 64;
constexpr int E    = 512;
constexpr int P    = 31;    // patch size
constexpr int S    = 200;   // canvas size
constexpr int HALF = 15;

// Tiling
constexpr int BAND    = 5;            // rows per canvas band (S % BAND == 0)
constexpr int NBANDS  = S / BAND;     // 40
constexpr int THREADS = 256;          // 4 waves
constexpr int NWAVES  = THREADS / 64;
constexpr int BATCH_E = 4;            // entries processed per wave-iteration
constexpr int KSLOT   = 3;            // 2 rows/slot * 3 slots >= BAND+1 rows

__global__ __launch_bounds__(THREADS, 8)   // 8 waves/SIMD -> VGPR <= 64
void imgs4dto3d_scatter_kernel(const float* __restrict__ img,
                               const int*   __restrict__ xyz,
                               float*       __restrict__ out)
{
    const int blk     = blockIdx.x;
    const int b       = blk / NBANDS;
    const int band    = blk % NBANDS;
    const int band_r0 = band * BAND;

    __shared__ __align__(16) float canvas[BAND * S];        // 4 KB
    __shared__ unsigned int list[E + NWAVES * BATCH_E];     // ~2.1 KB
    __shared__ int cnt;

    const int tid = threadIdx.x;
    if (tid == 0) cnt = 0;

    // zero the band (vectorized)
    {
        float4* cz = reinterpret_cast<float4*>(canvas);
        constexpr int NZ = (BAND * S) / 4;  // 250
        for (int i = tid; i < NZ; i += THREADS) cz[i] = make_float4(0.f, 0.f, 0.f, 0.f);
    }
    __syncthreads();

    // ---- Phase 1: compact intersecting emitters into LDS ----
    // pack: e[0:8] | i_lo[9:13] | lrow[14:17] | nrows[18:21] | c0[22:29]
    for (int e = tid; e < E; e += THREADS) {
        const int base3 = (b * E + e) * 3;
        const int x = xyz[base3 + 0];   // row center
        const int y = xyz[base3 + 1];   // col center
        const int r_lo = max(x - HALF, band_r0);
        const int r_hi = min(x + HALF + 1, band_r0 + BAND);
        if (r_lo < r_hi) {
            const unsigned i_lo  = (unsigned)(r_lo - (x - HALF));   // 0..30
            const unsigned lrow  = (unsigned)(r_lo - band_r0);      // 0..4
            const unsigned nrows = (unsigned)(r_hi - r_lo);         // 1..5
            const unsigned c0    = (unsigned)(y - HALF);            // 0..169
            const unsigned packed =
                (unsigned)e | (i_lo << 9) | (lrow << 14) | (nrows << 18) | (c0 << 22);
            list[atomicAdd(&cnt, 1)] = packed;
        }
    }
    __syncthreads();

    // pad list to a multiple of NWAVES*BATCH_E with nrows=0 dummies -> uniform loop
    const int n    = cnt;
    const int npad = (n + NWAVES * BATCH_E - 1) & ~(NWAVES * BATCH_E - 1);
    if (tid < npad - n) list[n + tid] = 0u;
    __syncthreads();

    // ---- Phase 2: scatter patch pixels into the LDS band, 4 entries at a time ----
    const int wid  = tid >> 6;
    const int lane = tid & 63;
    const int half = lane >> 5;        // row-pair half
    const int col  = lane & 31;        // 0..31
    const bool colact = (col < P);

    for (int idx0 = wid * BATCH_E; idx0 < npad; idx0 += NWAVES * BATCH_E) {
        unsigned pk[BATCH_E];
        #pragma unroll
        for (int u = 0; u < BATCH_E; ++u) pk[u] = list[idx0 + u];

        // stage 1: issue all predicated loads (12 in flight)
        float v[BATCH_E][KSLOT];
        bool  act[BATCH_E][KSLOT];
        #pragma unroll
        for (int u = 0; u < BATCH_E; ++u) {
            const int e     = (int)(pk[u] & 511u);
            const int i_lo  = (int)((pk[u] >> 9)  & 31u);
            const int nrows = (int)((pk[u] >> 18) & 15u);
            const float* src = img + (size_t)(b * E + e) * (P * P) + (size_t)i_lo * P;
            #pragma unroll
            for (int k = 0; k < KSLOT; ++k) {
                const int r = 2 * k + half;
                act[u][k] = colact && (r < nrows);
                v[u][k]   = act[u][k] ? src[r * P + col] : 0.0f;
            }
        }
        // stage 2: LDS atomics
        #pragma unroll
        for (int u = 0; u < BATCH_E; ++u) {
            const int lrow = (int)((pk[u] >> 14) & 15u);
            const int c0   = (int)(pk[u] >> 22);
            #pragma unroll
            for (int k = 0; k < KSLOT; ++k) {
                const int r = 2 * k + half;
                if (act[u][k]) atomicAdd(&canvas[(lrow + r) * S + (c0 + col)], v[u][k]);
            }
        }
    }
    __syncthreads();

    // ---- Phase 3: write the band out (each output pixel written exactly once) ----
    float4* outv = reinterpret_cast<float4*>(out + (size_t)b * (S * S) + (size_t)band_r0 * S);
    const float4* cv = reinterpret_cast<const float4*>(canvas);
    constexpr int NV4 = (BAND * S) / 4;   // 250
    for (int i = tid; i < NV4; i += THREADS) {
        outv[i] = cv[i];
    }
}

extern "C" void kernel_launch(void* const* d_in, const int* in_sizes, int n_in,
                              void* d_out, int out_size, void* d_ws, size_t ws_size,
                              hipStream_t stream)
{
    const float* img = (const float*)d_in[0];   // [B, E, P, P] fp32
    const int*   xyz = (const int*)d_in[1];     // [B, E, 3] int32
    float*       out = (float*)d_out;           // [B, 1, S, S] fp32

    imgs4dto3d_scatter_kernel<<<B * NBANDS, THREADS, 0, stream>>>(img, xyz, out);
}

// Round 5
// 100.064 us; speedup vs baseline: 1.9245x; 1.9245x over previous
//
#include <hip/hip_runtime.h>

// Problem constants (match reference)
constexpr int B    = 64;
constexpr int E    = 512;
constexpr int P    = 31;    // patch size
constexpr int S    = 200;   // canvas size
constexpr int HALF = 15;

// Gather tiling: one WAVE per 16x16 canvas tile, 4 tiles per block
constexpr int TS      = 16;
constexpr int NTD     = (S + TS - 1) / TS;    // 13 tiles per dim
constexpr int NTILES  = NTD * NTD;            // 169 tiles per batch
constexpr int THREADS = 256;                  // 4 waves = 4 tiles
constexpr int TPB     = 4;                    // tiles per block
constexpr int NBLK    = (NTILES + TPB - 1) / TPB;   // 43 blocks per batch

__global__ __launch_bounds__(THREADS, 8)
void imgs4dto3d_gather_kernel(const float* __restrict__ img,
                              const int*   __restrict__ xyz,
                              float*       __restrict__ out)
{
    const int b    = blockIdx.y;
    const int tid  = threadIdx.x;
    const int wid  = tid >> 6;
    const int lane = tid & 63;

    // ---- stage all emitters' (x,y) into LDS: int4 = two emitters ----
    __shared__ int4 xy2[E / 2];                 // 4 KB
    const int* xb = xyz + (size_t)b * E * 3;
    for (int i = tid; i < E / 2; i += THREADS) {
        const int* p = xb + 6 * i;
        xy2[i] = make_int4(p[0], p[1], p[3], p[4]);
    }
    __syncthreads();

    // ---- this wave's tile ----
    const int t  = blockIdx.x * TPB + wid;      // flattened tile index
    const bool live = (t < NTILES);
    const int tr = live ? (t / NTD) : 0;
    const int tc = live ? (t % NTD) : 0;
    const int r0 = live ? (tr * TS) : S;        // dead wave: r0=200 -> never active
    const int c0 = tc * TS;

    const int col  = lane & 15;                 // 0..15
    const int rowg = lane >> 4;                 // 0..3
    const int c    = c0 + col;
    const int rbase = r0 + rowg * 4;            // rows rbase..rbase+3

    float acc0 = 0.f, acc1 = 0.f, acc2 = 0.f, acc3 = 0.f;
    const size_t bbase = (size_t)b * E * (P * P);

    for (int h = 0; h < E / 2; ++h) {
        const int4 xy = xy2[h];                 // uniform address -> broadcast

        // emitter 2h
        {
            const int pc  = c + HALF - xy.y;
            const int prb = r0 + HALF - xy.x;   // pr for row r0
            const bool colok = (unsigned)pc <= 30u;
            const bool rowok = (unsigned)(prb + 15) <= 45u;  // some row in tile active
            if (__any(colok && rowok)) {
                const size_t base = bbase + (size_t)(2 * h) * (P * P);
                const int pr0 = prb + rowg * 4;
                const bool a0 = colok && ((unsigned)(pr0 + 0) <= 30u);
                const bool a1 = colok && ((unsigned)(pr0 + 1) <= 30u);
                const bool a2 = colok && ((unsigned)(pr0 + 2) <= 30u);
                const bool a3 = colok && ((unsigned)(pr0 + 3) <= 30u);
                const float v0 = a0 ? img[base + (pr0 + 0) * P + pc] : 0.f;
                const float v1 = a1 ? img[base + (pr0 + 1) * P + pc] : 0.f;
                const float v2 = a2 ? img[base + (pr0 + 2) * P + pc] : 0.f;
                const float v3 = a3 ? img[base + (pr0 + 3) * P + pc] : 0.f;
                acc0 += v0; acc1 += v1; acc2 += v2; acc3 += v3;
            }
        }
        // emitter 2h+1
        {
            const int pc  = c + HALF - xy.w;
            const int prb = r0 + HALF - xy.z;
            const bool colok = (unsigned)pc <= 30u;
            const bool rowok = (unsigned)(prb + 15) <= 45u;
            if (__any(colok && rowok)) {
                const size_t base = bbase + (size_t)(2 * h + 1) * (P * P);
                const int pr0 = prb + rowg * 4;
                const bool a0 = colok && ((unsigned)(pr0 + 0) <= 30u);
                const bool a1 = colok && ((unsigned)(pr0 + 1) <= 30u);
                const bool a2 = colok && ((unsigned)(pr0 + 2) <= 30u);
                const bool a3 = colok && ((unsigned)(pr0 + 3) <= 30u);
                const float v0 = a0 ? img[base + (pr0 + 0) * P + pc] : 0.f;
                const float v1 = a1 ? img[base + (pr0 + 1) * P + pc] : 0.f;
                const float v2 = a2 ? img[base + (pr0 + 2) * P + pc] : 0.f;
                const float v3 = a3 ? img[base + (pr0 + 3) * P + pc] : 0.f;
                acc0 += v0; acc1 += v1; acc2 += v2; acc3 += v3;
            }
        }
    }

    // ---- store: each live thread writes its 4 pixels (each pixel exactly once) ----
    if (live) {
        float accs[4] = {acc0, acc1, acc2, acc3};
        #pragma unroll
        for (int q = 0; q < 4; ++q) {
            const int r = rbase + q;
            if (r < S && c < S) {
                out[(size_t)b * (S * S) + r * S + c] = accs[q];
            }
        }
    }
}

extern "C" void kernel_launch(void* const* d_in, const int* in_sizes, int n_in,
                              void* d_out, int out_size, void* d_ws, size_t ws_size,
                              hipStream_t stream)
{
    const float* img = (const float*)d_in[0];   // [B, E, P, P] fp32
    const int*   xyz = (const int*)d_in[1];     // [B, E, 3] int32
    float*       out = (float*)d_out;           // [B, 1, S, S] fp32

    dim3 grid(NBLK, B);
    imgs4dto3d_gather_kernel<<<grid, THREADS, 0, stream>>>(img, xyz, out);
}

// Round 6
// 84.447 us; speedup vs baseline: 2.2804x; 1.1849x over previous
//
#include <hip/hip_runtime.h>

// Problem constants (match reference)
constexpr int B    = 64;
constexpr int E    = 512;
constexpr int P    = 31;    // patch size
constexpr int S    = 200;   // canvas size
constexpr int HALF = 15;

// Tiling
constexpr int TS     = 16;
constexpr int NTD    = (S + TS - 1) / TS;    // 13 tiles per dim
constexpr int NTILES = NTD * NTD;            // 169 tiles per batch
constexpr int NBINS  = B * NTILES;           // 10816
constexpr int CAP    = 128;                  // bin capacity (expected ~38, max ~65)

// Gather launch: one wave per tile, 4 tiles per 256-thread block
constexpr int TPB     = 4;
constexpr int THREADS = 256;
constexpr int NBLK    = (NTILES + TPB - 1) / TPB;   // 43

// ws layout: int counts[NBINS]; unsigned entries[NBINS * CAP]
// total = 43264 + 5537792 bytes ~= 5.6 MB

__global__ __launch_bounds__(512)
void imgs4dto3d_bin_kernel(const int* __restrict__ xyz,
                           int*       __restrict__ counts,
                           unsigned*  __restrict__ entries)
{
    const int b = blockIdx.x;
    const int e = threadIdx.x;
    const int x = xyz[(size_t)(b * E + e) * 3 + 0];
    const int y = xyz[(size_t)(b * E + e) * 3 + 1];
    // one record per emitter, identical for every bin it lands in
    const unsigned pk = (unsigned)e | ((unsigned)x << 9) | ((unsigned)y << 17);

    // tile range overlapped by the 31x31 patch (x in [15,184] -> no clipping needed)
    const int tr_lo = (x - HALF) >> 4, tr_hi = (x + HALF) >> 4;   // 0..12
    const int tc_lo = (y - HALF) >> 4, tc_hi = (y + HALF) >> 4;

    for (int tr = tr_lo; tr <= tr_hi; ++tr) {
        for (int tc = tc_lo; tc <= tc_hi; ++tc) {
            const int bin = b * NTILES + tr * NTD + tc;
            const int pos = atomicAdd(&counts[bin], 1);
            if (pos < CAP) entries[(size_t)bin * CAP + pos] = pk;
        }
    }
}

__global__ __launch_bounds__(THREADS, 8)
void imgs4dto3d_gather_kernel(const float*    __restrict__ img,
                              const int*      __restrict__ counts,
                              const unsigned* __restrict__ entries,
                              float*          __restrict__ out)
{
    const int b    = blockIdx.y;
    const int tid  = threadIdx.x;
    const int wid  = tid >> 6;
    const int lane = tid & 63;

    const int t    = blockIdx.x * TPB + wid;
    const bool live = (t < NTILES);
    const int tr = live ? (t / NTD) : 0;
    const int tc = live ? (t % NTD) : 0;
    const int r0 = tr * TS;
    const int c0 = tc * TS;

    const int col  = lane & 15;          // 0..15
    const int rowg = lane >> 4;          // 0..3 (rows rbase..rbase+3)
    const int c    = c0 + col;

    const int bin = live ? (b * NTILES + t) : 0;
    int n = live ? counts[bin] : 0;
    n = min(n, CAP);
    const uint4* lst = reinterpret_cast<const uint4*>(entries + (size_t)bin * CAP);

    float acc0 = 0.f, acc1 = 0.f, acc2 = 0.f, acc3 = 0.f;
    const size_t bbase = (size_t)b * E * (P * P);

    const int niter = (n + 3) >> 2;
    uint4 cur = (niter > 0) ? lst[0] : make_uint4(0u, 0u, 0u, 0u);
    for (int i = 0; i < niter; ++i) {
        const uint4 nxt = (i + 1 < niter) ? lst[i + 1] : cur;  // prefetch next entries
        const unsigned pks[4] = {cur.x, cur.y, cur.z, cur.w};
        #pragma unroll
        for (int u = 0; u < 4; ++u) {
            const bool inb = (4 * i + u) < n;          // wave-uniform
            const unsigned pk = pks[u];
            const int e = (int)(pk & 511u);
            const int x = (int)((pk >> 9) & 255u);
            const int y = (int)(pk >> 17);
            // verified round-5 index math
            const int pc  = c + HALF - y;              // patch col for this lane
            const int pr0 = r0 + HALF - x + rowg * 4;  // patch row for q=0
            const bool colok = inb && ((unsigned)pc <= 30u);
            const size_t base = bbase + (size_t)e * (P * P);
            const bool a0 = colok && ((unsigned)(pr0 + 0) <= 30u);
            const bool a1 = colok && ((unsigned)(pr0 + 1) <= 30u);
            const bool a2 = colok && ((unsigned)(pr0 + 2) <= 30u);
            const bool a3 = colok && ((unsigned)(pr0 + 3) <= 30u);
            const float v0 = a0 ? img[base + (pr0 + 0) * P + pc] : 0.f;
            const float v1 = a1 ? img[base + (pr0 + 1) * P + pc] : 0.f;
            const float v2 = a2 ? img[base + (pr0 + 2) * P + pc] : 0.f;
            const float v3 = a3 ? img[base + (pr0 + 3) * P + pc] : 0.f;
            acc0 += v0; acc1 += v1; acc2 += v2; acc3 += v3;
        }
        cur = nxt;
    }

    // store: each live thread writes its 4 pixels (each canvas pixel exactly once)
    if (live) {
        const int rbase = r0 + rowg * 4;
        float accs[4] = {acc0, acc1, acc2, acc3};
        #pragma unroll
        for (int q = 0; q < 4; ++q) {
            const int r = rbase + q;
            if (r < S && c < S) {
                out[(size_t)b * (S * S) + r * S + c] = accs[q];
            }
        }
    }
}

extern "C" void kernel_launch(void* const* d_in, const int* in_sizes, int n_in,
                              void* d_out, int out_size, void* d_ws, size_t ws_size,
                              hipStream_t stream)
{
    const float* img = (const float*)d_in[0];   // [B, E, P, P] fp32
    const int*   xyz = (const int*)d_in[1];     // [B, E, 3] int32
    float*       out = (float*)d_out;           // [B, 1, S, S] fp32

    int*      counts  = (int*)d_ws;
    unsigned* entries = (unsigned*)d_ws + NBINS;

    // zero the bin counters every call (deterministic; entries gated by counts)
    hipMemsetAsync(counts, 0, (size_t)NBINS * sizeof(int), stream);

    imgs4dto3d_bin_kernel<<<B, E, 0, stream>>>(xyz, counts, entries);

    dim3 grid(NBLK, B);
    imgs4dto3d_gather_kernel<<<grid, THREADS, 0, stream>>>(img, counts, entries, out);
}